// Round 2
// baseline (2564.631 us; speedup 1.0000x reference)
//
#include <hip/hip_runtime.h>

#define NEG9 (-1e9f)
#define K2E  2.885390081777927f    /* 2*log2(e): tanh(z)=1-2/(1+exp2(K2E*z)) */
#define L2E  1.4426950408889634f
#define LN2f 0.6931471805599453f

#define OUT_SEL  16777216
#define OUT_HF   16908288
#define OUT_CF   17039360

typedef _Float16 half2_t __attribute__((ext_vector_type(2)));

static __device__ __forceinline__ float fexp2(float x){
#if __has_builtin(__builtin_amdgcn_exp2f)
  return __builtin_amdgcn_exp2f(x);
#else
  return exp2f(x);
#endif
}
static __device__ __forceinline__ float frcp(float x){
#if __has_builtin(__builtin_amdgcn_rcpf)
  return __builtin_amdgcn_rcpf(x);
#else
  return 1.0f / x;
#endif
}
static __device__ __forceinline__ float flog2(float x){
#if __has_builtin(__builtin_amdgcn_logf)
  return __builtin_amdgcn_logf(x);
#else
  return log2f(x);
#endif
}
static __device__ __forceinline__ uint pk16(float a, float b){
#if __has_builtin(__builtin_amdgcn_cvt_pkrtz)
  auto h = __builtin_amdgcn_cvt_pkrtz(a, b);           /* v_cvt_pkrtz_f16_f32 */
  union U { decltype(h) h2; uint u; } c; c.h2 = h; return c.u;
#else
  union { _Float16 h[2]; uint u; } c; c.h[0] = (_Float16)a; c.h[1] = (_Float16)b; return c.u;
#endif
}
static __device__ __forceinline__ float2 up16(uint u){
  union { uint u; _Float16 h[2]; } c; c.u = u;
  return make_float2((float)c.h[0], (float)c.h[1]);
}
static __device__ __forceinline__ float fdot2(uint a, uint b, float acc){
#if __has_builtin(__builtin_amdgcn_fdot2)
  union { uint u; half2_t h; } ua, ub; ua.u = a; ub.u = b;
  return __builtin_amdgcn_fdot2(ua.h, ub.h, acc, false);
#else
  float2 fa = up16(a), fb = up16(b);
  return acc + fa.x * fb.x + fa.y * fb.y;
#endif
}
static __device__ __forceinline__ float dot8v(uint4 w, uint4 x, float acc){
  acc = fdot2(w.x, x.x, acc); acc = fdot2(w.y, x.y, acc);
  acc = fdot2(w.z, x.z, acc); acc = fdot2(w.w, x.w, acc);
  return acc;
}
static __device__ __forceinline__ float rdlane(float v, int i){
#if __has_builtin(__builtin_amdgcn_readlane)
  return __uint_as_float(__builtin_amdgcn_readlane(__float_as_uint(v), i));
#else
  return __shfl(v, i, 64);
#endif
}
static __device__ __forceinline__ float sigm(float x){
  return frcp(1.0f + fexp2(-L2E * x));
}
static __device__ __forceinline__ float tanh_(float x){
  return 1.0f - 2.0f * frcp(1.0f + fexp2(K2E * x));
}

/* T2 XOR-swizzle for [128 rows][256B rows] f16 tiles (stored as uint arrays).
   byte_in_row ^= (row&7)<<4 */
#define SWU32(r, d)  (((r)<<6) | ((d) ^ (((r)&7)<<2)))   /* uint index  */
#define SWU128(r, c) (((r)<<4) | ((c) ^ ((r)&7)))        /* uint4 index */
/* W_hh rows are read in even/odd pairs -> swizzle on (o>>1) */
#define WHU128(o, c) (((o)<<4) | ((c) ^ (((o)>>1)&7)))

/* =====================================================================
 * K1: LSTM chain. 4 rows/block, 128 steps. Also computes Kqq = K2E*(h2@gWq.T+gbq)
 * into out[b][t][:] (reused by K2 stage1, later overwritten by log_p).
 * ===================================================================== */
__global__ __launch_bounds__(512, 1) void k_lstm(
    const float* __restrict__ dec, const float* __restrict__ emb,
    const float* __restrict__ h0g, const float* __restrict__ c0g,
    const float* __restrict__ W_ih, const float* __restrict__ W_hh,
    const float* __restrict__ b_ih, const float* __restrict__ b_hh,
    const float* __restrict__ gWq, const float* __restrict__ gbq,
    const int* __restrict__ eval, float* __restrict__ out)
{
  __shared__ __align__(16) uint  sWhh[32768];      /* 128 KiB f16 [512][64dw], swizzled */
  __shared__ __align__(16) uint  sXh[4][128];      /* f16 pairs: dw0..63 = x, 64..127 = h */
  __shared__ __align__(16) float sScr[2][4][512];  /* 16 KiB partial gates */
  __shared__ float sC[4][128];
  __shared__ int   sEval[4][128];

  const int tid = threadIdx.x;
  const int b0  = blockIdx.x * 4;
  const int m = tid & 127, r = tid >> 7;
  const int p = tid & 255, s = tid >> 8;

  /* ---- init: pack W_hh to f16 LDS ---- */
  {
    const int row = tid;
    const float4* src = (const float4*)(W_hh + row * 128);
    for (int c = 0; c < 16; ++c) {
      float4 a = src[2*c], bb = src[2*c+1];
      uint4 wv;
      wv.x = pk16(a.x, a.y);  wv.y = pk16(a.z, a.w);
      wv.z = pk16(bb.x, bb.y); wv.w = pk16(bb.z, bb.w);
      ((uint4*)sWhh)[WHU128(row, c)] = wv;
    }
  }
  {
    float hv = h0g[(b0 + r) * 128 + m];
    ((ushort*)sXh)[r * 256 + 128 + m] = (ushort)(pk16(hv, hv) & 0xffffu);
    sC[r][m] = c0g[(b0 + r) * 128 + m];
    int ev = eval[(b0 + r) * 128 + m];
    sEval[r][m] = ev;
    out[OUT_SEL + (b0 + r) * 128 + m] = (float)ev;
    if (m < 64) {
      float2 xv = *(const float2*)(dec + (b0 + r) * 128 + 2 * m);
      sXh[r][m] = pk16(xv.x, xv.y);
    }
  }
  __syncthreads();

  for (int t = 0; t < 128; ++t) {
    /* ---- dot phase: s=0 -> x@W_ih.T (global stream), s=1 -> h@W_hh.T (LDS) ---- */
    float acc[4][2];
#pragma unroll
    for (int rr = 0; rr < 4; ++rr) { acc[rr][0] = 0.f; acc[rr][1] = 0.f; }
    if (s == 0) {
      const float4* w0 = (const float4*)(W_ih + (size_t)(2*p) * 128);
      const float4* w1 = (const float4*)(W_ih + (size_t)(2*p+1) * 128);
      for (int c = 0; c < 16; ++c) {
        float4 a0 = w0[2*c], a1 = w0[2*c+1];
        float4 e0 = w1[2*c], e1 = w1[2*c+1];
        uint4 wA, wB;
        wA.x = pk16(a0.x,a0.y); wA.y = pk16(a0.z,a0.w); wA.z = pk16(a1.x,a1.y); wA.w = pk16(a1.z,a1.w);
        wB.x = pk16(e0.x,e0.y); wB.y = pk16(e0.z,e0.w); wB.z = pk16(e1.x,e1.y); wB.w = pk16(e1.z,e1.w);
#pragma unroll
        for (int rr = 0; rr < 4; ++rr) {
          uint4 x4 = *(const uint4*)&sXh[rr][c * 4];
          acc[rr][0] = dot8v(wA, x4, acc[rr][0]);
          acc[rr][1] = dot8v(wB, x4, acc[rr][1]);
        }
      }
    } else {
      for (int c = 0; c < 16; ++c) {
        uint4 wA = ((const uint4*)sWhh)[WHU128(2*p,   c)];
        uint4 wB = ((const uint4*)sWhh)[WHU128(2*p+1, c)];
#pragma unroll
        for (int rr = 0; rr < 4; ++rr) {
          uint4 x4 = *(const uint4*)&sXh[rr][64 + c * 4];
          acc[rr][0] = dot8v(wA, x4, acc[rr][0]);
          acc[rr][1] = dot8v(wB, x4, acc[rr][1]);
        }
      }
    }
#pragma unroll
    for (int rr = 0; rr < 4; ++rr)
      *(float2*)&sScr[s][rr][2*p] = make_float2(acc[rr][0], acc[rr][1]);
    __syncthreads();

    /* ---- combine: gates i,f,g,o -> c,h update (f32) ---- */
    float pre0 = sScr[0][r][m      ] + sScr[1][r][m      ] + b_ih[m      ] + b_hh[m      ];
    float pre1 = sScr[0][r][m + 128] + sScr[1][r][m + 128] + b_ih[m + 128] + b_hh[m + 128];
    float pre2 = sScr[0][r][m + 256] + sScr[1][r][m + 256] + b_ih[m + 256] + b_hh[m + 256];
    float pre3 = sScr[0][r][m + 384] + sScr[1][r][m + 384] + b_ih[m + 384] + b_hh[m + 384];
    float ii = sigm(pre0), ff = sigm(pre1), gg = tanh_(pre2), oo = sigm(pre3);
    float cc = ff * sC[r][m] + ii * gg;
    sC[r][m] = cc;
    float hh = oo * tanh_(cc);
    ((ushort*)sXh)[r*256 + 128 + m] = (ushort)(pk16(hh, hh) & 0xffffu);
    if (t == 127) {
      out[OUT_HF + (b0+r)*128 + m] = hh;
      out[OUT_CF + (b0+r)*128 + m] = cc;
    } else if (m < 64) {
      int idx = sEval[r][t];      /* x_{t+1} = embedded[idx_t] (teacher forcing) */
      float2 xv = *(const float2*)(emb + (size_t)idx * 131072 + (b0+r)*128 + 2*m);
      sXh[r][m] = pk16(xv.x, xv.y);
    }
    __syncthreads();

    /* ---- glimpse query: Kqq = K2E*(h2@gWq.T + gbq) -> out[b][t][:] ---- */
    {
      const float4* wq = (const float4*)(gWq + (size_t)m * 128);
      float qa = 0.f;
      for (int c = 0; c < 16; ++c) {
        float4 a0 = wq[2*c], a1 = wq[2*c+1];
        uint4 qw;
        qw.x = pk16(a0.x,a0.y); qw.y = pk16(a0.z,a0.w); qw.z = pk16(a1.x,a1.y); qw.w = pk16(a1.z,a1.w);
        uint4 h4 = *(const uint4*)&sXh[r][64 + c*4];
        qa = dot8v(qw, h4, qa);
      }
      out[(size_t)(b0+r) * 16384 + (size_t)t * 128 + m] = K2E * (qa + gbq[m]);
    }
    __syncthreads();
  }
}

/* =====================================================================
 * K2: per-batch-row attention, stage-restructured (1 row/block).
 * B0: E_g=exp2(K*e_g)  -> later G_L
 * B1: e_g (raw)        -> later Kqq_p
 * B2: E_p=exp2(K*e_p)
 * B3: ctx-stage / P[t][l] / pWq-f16
 * ===================================================================== */
__global__ __launch_bounds__(512, 1) void k_attn(
    const float* __restrict__ ctx,
    const float* __restrict__ gWref, const float* __restrict__ gbref,
    const float* __restrict__ gv,
    const float* __restrict__ pWq, const float* __restrict__ pbq,
    const float* __restrict__ pWref, const float* __restrict__ pbref,
    const float* __restrict__ pv,
    const int* __restrict__ eval,
    float* __restrict__ out)
{
  __shared__ __align__(16) uint sB0[8192];
  __shared__ __align__(16) uint sB1[8192];
  __shared__ __align__(16) uint sB2[8192];
  __shared__ __align__(16) uint sB3[8192];

  const int tid  = threadIdx.x;
  const int b    = blockIdx.x;
  const int lane = tid & 63, wv = tid >> 6;

  /* ---- rank (inverse tour permutation): masked at step t iff rank[l] < t ---- */
  if (tid < 128) {
    int ev = eval[b * 128 + tid];
    sB3[4096 + ev] = (uint)tid;
  }
  __syncthreads();
  const int rank0 = (int)sB3[4096 + 2*lane];
  const int rank1 = (int)sB3[4096 + 2*lane + 1];

  float Sgv = 0.f, Spv = 0.f;
  for (int i = 0; i < 128; i += 4) {
    float4 g4 = *(const float4*)(gv + i); Sgv += g4.x + g4.y + g4.z + g4.w;
    float4 p4 = *(const float4*)(pv + i); Spv += p4.x + p4.y + p4.z + p4.w;
  }
  const float G2a = 2.f * gv[2*lane], G2b = 2.f * gv[2*lane+1];
  const float P2a = 2.f * pv[2*lane], P2b = 2.f * pv[2*lane+1];

  /* ---- init: e_g / E_g / E_p from context + Wref ---- */
  {
    float* ctxS = (float*)sB3;            /* [32][128] f32 staging (first 16 KiB) */
    const int o = tid & 127, lq = tid >> 7;
    for (int ch = 0; ch < 4; ++ch) {
      __syncthreads();
      {
        int li = tid >> 4, h8 = (tid & 15) * 8;
        const float* src = ctx + (size_t)(ch*32 + li) * 131072 + (size_t)b * 128 + h8;
        *(float4*)&ctxS[li*128 + h8]     = *(const float4*)src;
        *(float4*)&ctxS[li*128 + h8 + 4] = *(const float4*)(src + 4);
      }
      __syncthreads();
      for (int mat = 0; mat < 2; ++mat) {
        const float* W    = mat ? pWref : gWref;
        const float* bias = mat ? pbref : gbref;
        float acc[8];
#pragma unroll
        for (int j = 0; j < 8; ++j) acc[j] = 0.f;
        const float4* wrow = (const float4*)(W + (size_t)o * 128);
        for (int c = 0; c < 16; ++c) {
          float4 w0 = wrow[2*c], w1 = wrow[2*c+1];
#pragma unroll
          for (int j = 0; j < 8; ++j) {
            const float4* cx = (const float4*)(ctxS + (lq*8 + j)*128 + c*8);
            float4 x0 = cx[0], x1 = cx[1];
            acc[j] += w0.x*x0.x + w0.y*x0.y + w0.z*x0.z + w0.w*x0.w
                    + w1.x*x1.x + w1.y*x1.y + w1.z*x1.z + w1.w*x1.w;
          }
        }
        float bo = bias[o];
        float ev[8];
#pragma unroll
        for (int j = 0; j < 8; ++j) ev[j] = acc[j] + bo;
        uint4 ex;
        ex.x = pk16(fexp2(K2E*ev[0]), fexp2(K2E*ev[1]));
        ex.y = pk16(fexp2(K2E*ev[2]), fexp2(K2E*ev[3]));
        ex.z = pk16(fexp2(K2E*ev[4]), fexp2(K2E*ev[5]));
        ex.w = pk16(fexp2(K2E*ev[6]), fexp2(K2E*ev[7]));
        int c0 = ch*4 + lq;
        if (mat == 0) {
          uint4 raw;
          raw.x = pk16(ev[0], ev[1]); raw.y = pk16(ev[2], ev[3]);
          raw.z = pk16(ev[4], ev[5]); raw.w = pk16(ev[6], ev[7]);
          ((uint4*)sB1)[SWU128(o, c0)] = raw;
          ((uint4*)sB0)[SWU128(o, c0)] = ex;
        } else {
          ((uint4*)sB2)[SWU128(o, c0)] = ex;
        }
      }
    }
  }
  __syncthreads();

  /* ---- stage1: all steps' glimpse logits + softmax -> P[t][l] in B3 ----
     u_g[t][l] = Sgv - sum_h 2gv[h] * rcp(1 + A[t][h]*E_g[h][l]),  A = exp2(Kqq) */
  for (int it = 0; it < 16; ++it) {
    const int t = it * 8 + wv;
    float2 kq = *(const float2*)(out + (size_t)b*16384 + (size_t)t*128 + 2*lane);
    float A0 = fexp2(kq.x), A1 = fexp2(kq.y);
    float acc0 = 0.f, acc1 = 0.f;
#pragma unroll 4
    for (int hp = 0; hp < 64; ++hp) {
      uint eA = sB0[SWU32(2*hp,   lane)];
      uint eB = sB0[SWU32(2*hp+1, lane)];
      float Ah0 = rdlane(A0, hp), Ah1 = rdlane(A1, hp);
      float g0  = rdlane(G2a, hp), g1 = rdlane(G2b, hp);
      float2 E = up16(eA);
      acc0 += g0 * frcp(fmaf(Ah0, E.x, 1.f));
      acc1 += g0 * frcp(fmaf(Ah0, E.y, 1.f));
      float2 F = up16(eB);
      acc0 += g1 * frcp(fmaf(Ah1, F.x, 1.f));
      acc1 += g1 * frcp(fmaf(Ah1, F.y, 1.f));
    }
    float u0 = Sgv - acc0, u1 = Sgv - acc1;
    if (rank0 < t) u0 = NEG9;
    if (rank1 < t) u1 = NEG9;
    float mx = fmaxf(u0, u1);
#pragma unroll
    for (int off = 32; off; off >>= 1) mx = fmaxf(mx, __shfl_xor(mx, off, 64));
    float ex0 = fexp2((u0 - mx) * L2E), ex1 = fexp2((u1 - mx) * L2E);
    float sm = ex0 + ex1;
#pragma unroll
    for (int off = 32; off; off >>= 1) sm += __shfl_xor(sm, off, 64);
    float rs = frcp(sm);
    sB3[SWU32(t, lane)] = pk16(ex0 * rs, ex1 * rs);
  }
  __syncthreads();

  /* ---- stage2: G_L[t][h] = sum_l e_g[h][l] * P[t][l]  (f16 dot2 GEMM) -> B0 ---- */
  {
    const int hq = tid & 31, tg = tid >> 5;
    float acc[4][8];
#pragma unroll
    for (int j = 0; j < 4; ++j)
#pragma unroll
      for (int tt = 0; tt < 8; ++tt) acc[j][tt] = 0.f;
    for (int c = 0; c < 16; ++c) {
      uint4 eR[4];
#pragma unroll
      for (int j = 0; j < 4; ++j) eR[j] = ((const uint4*)sB1)[SWU128(hq*4 + j, c)];
#pragma unroll
      for (int tt = 0; tt < 8; ++tt) {
        uint4 pp = ((const uint4*)sB3)[SWU128(tg*8 + tt, c)];
#pragma unroll
        for (int j = 0; j < 4; ++j) acc[j][tt] = dot8v(eR[j], pp, acc[j][tt]);
      }
    }
#pragma unroll
    for (int tt = 0; tt < 8; ++tt) {
      int t = tg*8 + tt;
      sB0[SWU32(t, 2*hq)]     = pk16(acc[0][tt], acc[1][tt]);
      sB0[SWU32(t, 2*hq + 1)] = pk16(acc[2][tt], acc[3][tt]);
    }
  }
  __syncthreads();

  /* ---- stage pWq -> f16 into B3 (P dead) ---- */
  {
    int oo = tid >> 2, seg = (tid & 3) * 32;
    const float4* src = (const float4*)(pWq + (size_t)oo * 128 + seg);
    for (int q = 0; q < 4; ++q) {
      float4 a = src[2*q], bb = src[2*q+1];
      uint4 v;
      v.x = pk16(a.x, a.y);  v.y = pk16(a.z, a.w);
      v.z = pk16(bb.x, bb.y); v.w = pk16(bb.z, bb.w);
      ((uint4*)sB3)[SWU128(oo, (seg >> 3) + q)] = v;
    }
  }
  __syncthreads();

  /* ---- stage3: Kqq_p[t][o] = K2E*(sum_h G_L[t][h]*pWq[o][h] + pbq[o]) -> B1 ---- */
  {
    const int oq = tid & 31, tg = tid >> 5;
    float acc[4][8];
#pragma unroll
    for (int j = 0; j < 4; ++j)
#pragma unroll
      for (int tt = 0; tt < 8; ++tt) acc[j][tt] = 0.f;
    for (int c = 0; c < 16; ++c) {
      uint4 wR[4];
#pragma unroll
      for (int j = 0; j < 4; ++j) wR[j] = ((const uint4*)sB3)[SWU128(oq*4 + j, c)];
#pragma unroll
      for (int tt = 0; tt < 8; ++tt) {
        uint4 gg = ((const uint4*)sB0)[SWU128(tg*8 + tt, c)];
#pragma unroll
        for (int j = 0; j < 4; ++j) acc[j][tt] = dot8v(wR[j], gg, acc[j][tt]);
      }
    }
    float bq0 = pbq[oq*4], bq1 = pbq[oq*4+1], bq2 = pbq[oq*4+2], bq3 = pbq[oq*4+3];
#pragma unroll
    for (int tt = 0; tt < 8; ++tt) {
      int t = tg*8 + tt;
      sB1[SWU32(t, 2*oq)]     = pk16(K2E*(acc[0][tt]+bq0), K2E*(acc[1][tt]+bq1));
      sB1[SWU32(t, 2*oq + 1)] = pk16(K2E*(acc[2][tt]+bq2), K2E*(acc[3][tt]+bq3));
    }
  }
  __syncthreads();

  /* ---- stage4: pointer logits + log_softmax -> out[b][t][:] ---- */
  for (int it = 0; it < 16; ++it) {
    const int t = it * 8 + wv;
    float2 kqp = up16(sB1[SWU32(t, lane)]);
    float A0 = fexp2(kqp.x), A1 = fexp2(kqp.y);
    float acc0 = 0.f, acc1 = 0.f;
#pragma unroll 4
    for (int hp = 0; hp < 64; ++hp) {
      uint eA = sB2[SWU32(2*hp,   lane)];
      uint eB = sB2[SWU32(2*hp+1, lane)];
      float Ah0 = rdlane(A0, hp), Ah1 = rdlane(A1, hp);
      float g0  = rdlane(P2a, hp), g1 = rdlane(P2b, hp);
      float2 E = up16(eA);
      acc0 += g0 * frcp(fmaf(Ah0, E.x, 1.f));
      acc1 += g0 * frcp(fmaf(Ah0, E.y, 1.f));
      float2 F = up16(eB);
      acc0 += g1 * frcp(fmaf(Ah1, F.x, 1.f));
      acc1 += g1 * frcp(fmaf(Ah1, F.y, 1.f));
    }
    float u0 = Spv - acc0, u1 = Spv - acc1;
    /* logits = 10*tanh(u) = 10 - 20*rcp(1+exp2(K*u)) */
    float lg0 = fmaf(-20.f, frcp(1.f + fexp2(K2E * u0)), 10.f);
    float lg1 = fmaf(-20.f, frcp(1.f + fexp2(K2E * u1)), 10.f);
    if (rank0 < t) lg0 = NEG9;
    if (rank1 < t) lg1 = NEG9;
    float mx = fmaxf(lg0, lg1);
#pragma unroll
    for (int off = 32; off; off >>= 1) mx = fmaxf(mx, __shfl_xor(mx, off, 64));
    float ex0 = fexp2((lg0 - mx) * L2E), ex1 = fexp2((lg1 - mx) * L2E);
    float sm = ex0 + ex1;
#pragma unroll
    for (int off = 32; off; off >>= 1) sm += __shfl_xor(sm, off, 64);
    float lnS = flog2(sm) * LN2f;
    float2 res = make_float2(lg0 - mx - lnS, lg1 - mx - lnS);
    *(float2*)(out + (size_t)b*16384 + (size_t)t*128 + 2*lane) = res;
  }
}

extern "C" void kernel_launch(void* const* d_in, const int* in_sizes, int n_in,
                              void* d_out, int out_size, void* d_ws, size_t ws_size,
                              hipStream_t stream) {
  const float* dec   = (const float*)d_in[0];
  const float* emb   = (const float*)d_in[1];
  const float* h0    = (const float*)d_in[2];
  const float* c0    = (const float*)d_in[3];
  const float* ctx   = (const float*)d_in[4];
  const float* W_ih  = (const float*)d_in[5];
  const float* W_hh  = (const float*)d_in[6];
  const float* b_ih  = (const float*)d_in[7];
  const float* b_hh  = (const float*)d_in[8];
  const float* gWq   = (const float*)d_in[9];
  const float* gbq   = (const float*)d_in[10];
  const float* gWref = (const float*)d_in[11];
  const float* gbref = (const float*)d_in[12];
  const float* gv    = (const float*)d_in[13];
  const float* pWq   = (const float*)d_in[14];
  const float* pbq   = (const float*)d_in[15];
  const float* pWref = (const float*)d_in[16];
  const float* pbref = (const float*)d_in[17];
  const float* pv    = (const float*)d_in[18];
  const int*   eval  = (const int*)d_in[19];
  float* out = (float*)d_out;
  (void)in_sizes; (void)n_in; (void)out_size; (void)d_ws; (void)ws_size;

  hipLaunchKernelGGL(k_lstm, dim3(256), dim3(512), 0, stream,
                     dec, emb, h0, c0, W_ih, W_hh, b_ih, b_hh, gWq, gbq, eval, out);
  hipLaunchKernelGGL(k_attn, dim3(1024), dim3(512), 0, stream,
                     ctx, gWref, gbref, gv, pWq, pbq, pWref, pbref, pv, eval, out);
}

// Round 5
// 1649.517 us; speedup vs baseline: 1.5548x; 1.5548x over previous
//
#include <hip/hip_runtime.h>

#define NEG9 (-1e9f)
#define K2E  2.885390081777927f    /* 2*log2(e): tanh(z)=1-2/(1+exp2(K2E*z)) */
#define L2E  1.4426950408889634f
#define LN2f 0.6931471805599453f

#define OUT_SEL  16777216
#define OUT_HF   16908288
#define OUT_CF   17039360

typedef _Float16 half2_t __attribute__((ext_vector_type(2)));

static __device__ __forceinline__ float fexp2(float x){
#if __has_builtin(__builtin_amdgcn_exp2f)
  return __builtin_amdgcn_exp2f(x);
#else
  return exp2f(x);
#endif
}
static __device__ __forceinline__ float frcp(float x){
#if __has_builtin(__builtin_amdgcn_rcpf)
  return __builtin_amdgcn_rcpf(x);
#else
  return 1.0f / x;
#endif
}
static __device__ __forceinline__ float flog2(float x){
#if __has_builtin(__builtin_amdgcn_logf)
  return __builtin_amdgcn_logf(x);
#else
  return log2f(x);
#endif
}
static __device__ __forceinline__ uint pk16(float a, float b){
#if __has_builtin(__builtin_amdgcn_cvt_pkrtz)
  auto h = __builtin_amdgcn_cvt_pkrtz(a, b);           /* v_cvt_pkrtz_f16_f32 */
  union U { decltype(h) h2; uint u; } c; c.h2 = h; return c.u;
#else
  union { _Float16 h[2]; uint u; } c; c.h[0] = (_Float16)a; c.h[1] = (_Float16)b; return c.u;
#endif
}
static __device__ __forceinline__ ushort f16u(float a){
  return (ushort)(pk16(a, 0.f) & 0xffffu);
}
static __device__ __forceinline__ float2 up16(uint u){
  union { uint u; _Float16 h[2]; } c; c.u = u;
  return make_float2((float)c.h[0], (float)c.h[1]);
}
static __device__ __forceinline__ float fdot2(uint a, uint b, float acc){
#if __has_builtin(__builtin_amdgcn_fdot2)
  union { uint u; half2_t h; } ua, ub; ua.u = a; ub.u = b;
  return __builtin_amdgcn_fdot2(ua.h, ub.h, acc, false);
#else
  float2 fa = up16(a), fb = up16(b);
  return acc + fa.x * fb.x + fa.y * fb.y;
#endif
}
static __device__ __forceinline__ float dot8v(uint4 w, uint4 x, float acc){
  acc = fdot2(w.x, x.x, acc); acc = fdot2(w.y, x.y, acc);
  acc = fdot2(w.z, x.z, acc); acc = fdot2(w.w, x.w, acc);
  return acc;
}
static __device__ __forceinline__ float rdlane(float v, int i){
#if __has_builtin(__builtin_amdgcn_readlane)
  return __uint_as_float(__builtin_amdgcn_readlane(__float_as_uint(v), i));
#else
  return __shfl(v, i, 64);
#endif
}
static __device__ __forceinline__ float sigm(float x){
  return frcp(1.0f + fexp2(-L2E * x));
}
static __device__ __forceinline__ float tanh_(float x){
  return 1.0f - 2.0f * frcp(1.0f + fexp2(K2E * x));
}

/* swizzles for [128 rows][256B] f16 tiles.
   SWU*: standard (r&7) XOR (per-lane consecutive rows).
   SWT*: (r>>1)&7 XOR — for reads where lane L owns rows 2L,2L+1 (even rows
         would collapse to 4 slots under the standard pattern). */
#define SWU128(r,c) (((r)<<4)|((c)^((r)&7)))
#define SWT128(r,c) (((r)<<4)|((c)^(((r)>>1)&7)))
#define SWU32(r,d)  (((r)<<6)|((d)^(((r)&7)<<2)))
#define SB16(r,h)   (((r)<<7)|((((h)>>1)^(((r)&7)<<2))<<1)|((h)&1))
#define TB16(r,h)   (((r)<<7)|((((h)>>1)^((((r)>>1)&7)<<2))<<1)|((h)&1))

/* =====================================================================
 * K1: LSTM chain, 4 batch rows/block, 128 steps, 1024 threads.
 * Each thread holds ONE f16 weight row (W_ih or W_hh) in 16 uint4 regs.
 * Also emits Kqq = K2E*(h2@gWq.T + gbq) into out[b][t][:] for K2.
 * ===================================================================== */
__global__ __launch_bounds__(1024, 4) void k_lstm(
    const float* __restrict__ dec, const float* __restrict__ emb,
    const float* __restrict__ h0g, const float* __restrict__ c0g,
    const float* __restrict__ W_ih, const float* __restrict__ W_hh,
    const float* __restrict__ b_ih, const float* __restrict__ b_hh,
    const float* __restrict__ gWq, const float* __restrict__ gbq,
    const int* __restrict__ eval, float* __restrict__ out)
{
  __shared__ __align__(16) uint  sGwq[8192];       /* gWq f16 [128][128] swz: 32KB */
  __shared__ __align__(16) uint  sXbuf[4][64];     /* x f16 per row */
  __shared__ __align__(16) uint  sHbuf[4][64];     /* h f16 per row */
  __shared__ __align__(16) float sScr[2][4][512];  /* partial gates: 16KB */
  __shared__ float sC[4][128];
  __shared__ int   sEval[4][128];

  const int tid = threadIdx.x;
  const int b0  = blockIdx.x * 4;
  const int xh  = tid >> 9;        /* 0: x-side (W_ih), 1: h-side (W_hh) */
  const int o   = tid & 511;       /* gate-output row */

  /* ---- own weight row -> f16 regs (once) ---- */
  uint4 wrow[16];
  {
    const float4* src = (const float4*)((xh ? W_hh : W_ih) + (size_t)o * 128);
#pragma unroll
    for (int c = 0; c < 16; ++c) {
      float4 a = src[2*c], d = src[2*c+1];
      wrow[c] = make_uint4(pk16(a.x,a.y), pk16(a.z,a.w), pk16(d.x,d.y), pk16(d.z,d.w));
    }
  }
  /* ---- stage gWq f16 (swizzled) ---- */
  {
    int row = tid >> 3, hq = tid & 7;
    const float4* ws = (const float4*)(gWq + (size_t)row * 128 + hq * 16);
    float4 w0 = ws[0], w1 = ws[1], w2 = ws[2], w3 = ws[3];
    ((uint4*)sGwq)[SWU128(row, hq*2)] =
        make_uint4(pk16(w0.x,w0.y), pk16(w0.z,w0.w), pk16(w1.x,w1.y), pk16(w1.z,w1.w));
    ((uint4*)sGwq)[SWU128(row, hq*2+1)] =
        make_uint4(pk16(w2.x,w2.y), pk16(w2.z,w2.w), pk16(w3.x,w3.y), pk16(w3.z,w3.w));
  }
  /* ---- state init ---- */
  if (tid < 256) {
    int r = tid >> 6, d = tid & 63;
    float2 hv = *(const float2*)(h0g + (size_t)(b0+r)*128 + 2*d);
    sHbuf[r][d] = pk16(hv.x, hv.y);
    float2 xv = *(const float2*)(dec + (size_t)(b0+r)*128 + 2*d);
    sXbuf[r][d] = pk16(xv.x, xv.y);
  }
  if (tid >= 512) {
    int t2 = tid - 512, r = t2 >> 7, m = t2 & 127;
    sC[r][m] = c0g[(size_t)(b0+r)*128 + m];
    int ev = eval[(size_t)(b0+r)*128 + m];
    sEval[r][m] = ev;
    out[OUT_SEL + (size_t)(b0+r)*128 + m] = (float)ev;
  }
  const int rC = (tid >> 7) & 3, mC = tid & 127;
  float bi0=0,bi1=0,bi2=0,bi3=0, bh0=0,bh1=0,bh2=0,bh3=0, gbqv=0;
  if (tid < 512) {
    bi0 = b_ih[mC];     bh0 = b_hh[mC];
    bi1 = b_ih[128+mC]; bh1 = b_hh[128+mC];
    bi2 = b_ih[256+mC]; bh2 = b_hh[256+mC];
    bi3 = b_ih[384+mC]; bh3 = b_hh[384+mC];
    gbqv = gbq[mC];
  }
  __syncthreads();

  for (int t = 0; t < 128; ++t) {
    /* ---- phase1: gate dots (x-side from sXbuf, h-side from sHbuf) ---- */
    {
      const uint4* xb = (const uint4*)(xh ? &sHbuf[0][0] : &sXbuf[0][0]);
      float a0=0.f, a1=0.f, a2=0.f, a3=0.f;
#pragma unroll
      for (int c = 0; c < 16; ++c) {
        a0 = dot8v(wrow[c], xb[c],      a0);
        a1 = dot8v(wrow[c], xb[16+c],   a1);
        a2 = dot8v(wrow[c], xb[32+c],   a2);
        a3 = dot8v(wrow[c], xb[48+c],   a3);
      }
      sScr[xh][0][o] = a0; sScr[xh][1][o] = a1;
      sScr[xh][2][o] = a2; sScr[xh][3][o] = a3;
    }
    __syncthreads();

    /* ---- phase2: combine (tid<512) | x-prefetch (512..767) ---- */
    if (tid < 512) {
      float p0 = sScr[0][rC][mC]     + sScr[1][rC][mC]     + bi0 + bh0;
      float p1 = sScr[0][rC][128+mC] + sScr[1][rC][128+mC] + bi1 + bh1;
      float p2 = sScr[0][rC][256+mC] + sScr[1][rC][256+mC] + bi2 + bh2;
      float p3 = sScr[0][rC][384+mC] + sScr[1][rC][384+mC] + bi3 + bh3;
      float ii = sigm(p0), ff = sigm(p1), gg = tanh_(p2), oo = sigm(p3);
      float cc = ff * sC[rC][mC] + ii * gg;
      sC[rC][mC] = cc;
      float hh = oo * tanh_(cc);
      ((ushort*)sHbuf)[rC*128 + mC] = f16u(hh);
      if (t == 127) {
        out[OUT_HF + (size_t)(b0+rC)*128 + mC] = hh;
        out[OUT_CF + (size_t)(b0+rC)*128 + mC] = cc;
      }
    } else if (tid < 768) {
      int t2 = tid - 512, r = t2 >> 6, d = t2 & 63;
      int idx = sEval[r][t];       /* teacher forcing: x_{t+1} = emb[tour[t]] */
      float2 xv = *(const float2*)(emb + (size_t)idx*131072 + (size_t)(b0+r)*128 + 2*d);
      sXbuf[r][d] = pk16(xv.x, xv.y);
    }
    __syncthreads();

    /* ---- phase3: Kqq = K2E*(h2@gWq.T + gbq) -> out ---- */
    if (tid < 512) {
      const uint4* hb = (const uint4*)&sHbuf[rC][0];
      float qa = 0.f;
#pragma unroll
      for (int c = 0; c < 16; ++c)
        qa = dot8v(((const uint4*)sGwq)[SWU128(mC, c)], hb[c], qa);
      out[(size_t)(b0+rC)*16384 + (size_t)t*128 + mC] = K2E * (qa + gbqv);
    }
    __syncthreads();
  }
}

/* =====================================================================
 * K2: per-batch-row attention, 1024 threads, 16 waves (8 t per wave).
 * Buffers (32KB each):
 *  sEg : e_g f16 [o][l]      -> G_L f16 [t][h]
 *  sEx : E_g' f16 [l][h](T)  -> pWq f16 [o][h]
 *  sEpx: Wref f16 [o][h]     -> E_p' f16 [l][h](T)
 *  sP  : ctx f16 [l][h]      -> P f16 [t][l] -> qq_p f16 [t][o]
 * ===================================================================== */
static __device__ __forceinline__ void attn_core(
    const uint* __restrict__ Ebuf, int lane, float g0v, float g1v,
    const float* A0, const float* A1, float* acc0, float* acc1)
{
  for (int hq = 0; hq < 16; ++hq) {
    uint4 e0v = ((const uint4*)Ebuf)[SWT128(2*lane,   hq)];
    uint4 e1v = ((const uint4*)Ebuf)[SWT128(2*lane+1, hq)];
#define SUBSTEP(E0d, E1d, s) { \
    int hidx = hq*4 + (s); \
    float2 E0 = up16(E0d), E1 = up16(E1d); \
    float gh0 = rdlane(g0v, hidx), gh1 = rdlane(g1v, hidx); \
    _Pragma("unroll") \
    for (int j = 0; j < 8; ++j) { \
      float a0 = rdlane(A0[j], hidx), a1 = rdlane(A1[j], hidx); \
      acc0[j] += gh0*frcp(fmaf(a0, E0.x, 1.f)) + gh1*frcp(fmaf(a1, E0.y, 1.f)); \
      acc1[j] += gh0*frcp(fmaf(a0, E1.x, 1.f)) + gh1*frcp(fmaf(a1, E1.y, 1.f)); \
    } }
    SUBSTEP(e0v.x, e1v.x, 0)
    SUBSTEP(e0v.y, e1v.y, 1)
    SUBSTEP(e0v.z, e1v.z, 2)
    SUBSTEP(e0v.w, e1v.w, 3)
#undef SUBSTEP
  }
}

__global__ __launch_bounds__(1024, 4) void k_attn(
    const float* __restrict__ ctx,
    const float* __restrict__ gWref, const float* __restrict__ gbref,
    const float* __restrict__ gv,
    const float* __restrict__ pWq, const float* __restrict__ pbq,
    const float* __restrict__ pWref, const float* __restrict__ pbref,
    const float* __restrict__ pv,
    const int* __restrict__ eval,
    float* __restrict__ out)
{
  __shared__ __align__(16) uint sEg[8192];
  __shared__ __align__(16) uint sEx[8192];
  __shared__ __align__(16) uint sEpx[8192];
  __shared__ __align__(16) uint sP[8192];
  __shared__ int sRank[128];

  const int tid  = threadIdx.x;
  const int b    = blockIdx.x;
  const int lane = tid & 63, w = tid >> 6;

  if (tid < 128) sRank[eval[(size_t)b*128 + tid]] = tid;

  /* ---- stage ctx->sP f16 [l][h], gWref->sEpx f16 [o][h] ---- */
  {
    int row = tid >> 3, hq = tid & 7;
    const float4* cs = (const float4*)(ctx + (size_t)row*131072 + (size_t)b*128 + hq*16);
    float4 c0 = cs[0], c1 = cs[1], c2 = cs[2], c3 = cs[3];
    ((uint4*)sP)[SWU128(row, hq*2)] =
        make_uint4(pk16(c0.x,c0.y), pk16(c0.z,c0.w), pk16(c1.x,c1.y), pk16(c1.z,c1.w));
    ((uint4*)sP)[SWU128(row, hq*2+1)] =
        make_uint4(pk16(c2.x,c2.y), pk16(c2.z,c2.w), pk16(c3.x,c3.y), pk16(c3.z,c3.w));
    const float4* ws = (const float4*)(gWref + (size_t)row*128 + hq*16);
    float4 w0 = ws[0], w1 = ws[1], w2 = ws[2], w3 = ws[3];
    ((uint4*)sEpx)[SWU128(row, hq*2)] =
        make_uint4(pk16(w0.x,w0.y), pk16(w0.z,w0.w), pk16(w1.x,w1.y), pk16(w1.z,w1.w));
    ((uint4*)sEpx)[SWU128(row, hq*2+1)] =
        make_uint4(pk16(w2.x,w2.y), pk16(w2.z,w2.w), pk16(w3.x,w3.y), pk16(w3.z,w3.w));
  }
  float Sgv = 0.f, Spv = 0.f;
  for (int i = 0; i < 128; i += 4) {
    float4 g4 = *(const float4*)(gv + i); Sgv += g4.x + g4.y + g4.z + g4.w;
    float4 p4 = *(const float4*)(pv + i); Spv += p4.x + p4.y + p4.z + p4.w;
  }
  const float G2a = 2.f*gv[2*lane], G2b = 2.f*gv[2*lane+1];
  const float P2a = 2.f*pv[2*lane], P2b = 2.f*pv[2*lane+1];
  __syncthreads();
  const int rank0 = sRank[2*lane], rank1 = sRank[2*lane+1];

  /* 8 l-groups x 16 l's each = full 128 coverage (round-3 bug: was 8) */
  const int o_ = tid & 127, lgrp = tid >> 7, l0_ = lgrp * 16;

  /* ---- mat0: e_g [o][l] + E_g' [l][h] ---- */
  {
    uint4 wr[16];
#pragma unroll
    for (int c = 0; c < 16; ++c) wr[c] = ((const uint4*)sEpx)[SWU128(o_, c)];
    float bo = gbref[o_];
    float e[16];
#pragma unroll
    for (int j = 0; j < 16; ++j) {
      float a = 0.f;
#pragma unroll
      for (int c = 0; c < 16; ++c)
        a = dot8v(wr[c], ((const uint4*)sP)[SWU128(l0_+j, c)], a);
      e[j] = a + bo;
    }
    ((uint4*)sEg)[SWU128(o_, lgrp*2)] =
        make_uint4(pk16(e[0],e[1]), pk16(e[2],e[3]), pk16(e[4],e[5]), pk16(e[6],e[7]));
    ((uint4*)sEg)[SWU128(o_, lgrp*2+1)] =
        make_uint4(pk16(e[8],e[9]), pk16(e[10],e[11]), pk16(e[12],e[13]), pk16(e[14],e[15]));
#pragma unroll
    for (int j = 0; j < 16; ++j)
      ((ushort*)sEx)[TB16(l0_+j, o_)] = f16u(fexp2(K2E*e[j]));
  }
  __syncthreads();
  /* ---- restage pWref -> sEpx ---- */
  {
    int row = tid >> 3, hq = tid & 7;
    const float4* ws = (const float4*)(pWref + (size_t)row*128 + hq*16);
    float4 w0 = ws[0], w1 = ws[1], w2 = ws[2], w3 = ws[3];
    ((uint4*)sEpx)[SWU128(row, hq*2)] =
        make_uint4(pk16(w0.x,w0.y), pk16(w0.z,w0.w), pk16(w1.x,w1.y), pk16(w1.z,w1.w));
    ((uint4*)sEpx)[SWU128(row, hq*2+1)] =
        make_uint4(pk16(w2.x,w2.y), pk16(w2.z,w2.w), pk16(w3.x,w3.y), pk16(w3.z,w3.w));
  }
  __syncthreads();
  /* ---- mat1: e_p -> regs (full 16 l's per thread) ---- */
  float ep[16];
  {
    uint4 wr[16];
#pragma unroll
    for (int c = 0; c < 16; ++c) wr[c] = ((const uint4*)sEpx)[SWU128(o_, c)];
    float bo = pbref[o_];
#pragma unroll
    for (int j = 0; j < 16; ++j) {
      float a = 0.f;
#pragma unroll
      for (int c = 0; c < 16; ++c)
        a = dot8v(wr[c], ((const uint4*)sP)[SWU128(l0_+j, c)], a);
      ep[j] = a + bo;
    }
  }
  __syncthreads();
#pragma unroll
  for (int j = 0; j < 16; ++j)
    ((ushort*)sEpx)[TB16(l0_+j, o_)] = f16u(fexp2(K2E*ep[j]));   /* E_p' */

  /* ---- stage1: glimpse logits + softmax -> P [t][l] f16 ---- */
  {
    float A0[8], A1[8], acc0[8], acc1[8];
#pragma unroll
    for (int j = 0; j < 8; ++j) {
      float2 qq = *(const float2*)(out + (size_t)b*16384 + (size_t)(w*8+j)*128 + 2*lane);
      A0[j] = fexp2(qq.x); A1[j] = fexp2(qq.y);
      acc0[j] = 0.f; acc1[j] = 0.f;
    }
    attn_core(sEx, lane, G2a, G2b, A0, A1, acc0, acc1);
#pragma unroll
    for (int j = 0; j < 8; ++j) {
      int t = w*8 + j;
      float u0 = Sgv - acc0[j], u1 = Sgv - acc1[j];
      if (rank0 < t) u0 = NEG9;
      if (rank1 < t) u1 = NEG9;
      float mx = fmaxf(u0, u1);
#pragma unroll
      for (int off = 32; off; off >>= 1) mx = fmaxf(mx, __shfl_xor(mx, off, 64));
      float ex0 = fexp2((u0 - mx)*L2E), ex1 = fexp2((u1 - mx)*L2E);
      float sm = ex0 + ex1;
#pragma unroll
      for (int off = 32; off; off >>= 1) sm += __shfl_xor(sm, off, 64);
      float rs = frcp(sm);
      sP[SWU32(t, lane)] = pk16(ex0*rs, ex1*rs);
    }
  }
  __syncthreads();

  /* ---- stage2: G_L[t][h] = sum_l e_g[h][l]*P[t][l]; stage pWq->sEx ---- */
  {
    const int h = tid & 127, tgrp = tid >> 7;
    uint4 wr[16];
#pragma unroll
    for (int c = 0; c < 16; ++c) wr[c] = ((const uint4*)sEg)[SWU128(h, c)];
    {
      int row = tid >> 3, hq = tid & 7;
      const float4* ws = (const float4*)(pWq + (size_t)row*128 + hq*16);
      float4 w0 = ws[0], w1 = ws[1], w2 = ws[2], w3 = ws[3];
      ((uint4*)sEx)[SWU128(row, hq*2)] =
          make_uint4(pk16(w0.x,w0.y), pk16(w0.z,w0.w), pk16(w1.x,w1.y), pk16(w1.z,w1.w));
      ((uint4*)sEx)[SWU128(row, hq*2+1)] =
          make_uint4(pk16(w2.x,w2.y), pk16(w2.z,w2.w), pk16(w3.x,w3.y), pk16(w3.z,w3.w));
    }
    __syncthreads();          /* all e_g reads staged to regs; sEg now writable */
    for (int tt = 0; tt < 16; ++tt) {
      int t = tgrp*16 + tt;
      float a = 0.f;
#pragma unroll
      for (int c = 0; c < 16; ++c)
        a = dot8v(wr[c], ((const uint4*)sP)[SWU128(t, c)], a);
      ((ushort*)sEg)[SB16(t, h)] = f16u(a);
    }
  }
  __syncthreads();

  /* ---- stage3: qq_p[t][o] = K2E*(G_L[t]@pWq[o] + pbq[o]) -> sP [t][o] f16 ---- */
  {
    const int oq = tid & 127, tgrp = tid >> 7;
    uint4 wr[16];
#pragma unroll
    for (int c = 0; c < 16; ++c) wr[c] = ((const uint4*)sEx)[SWU128(oq, c)];
    float bo = pbq[oq];
    for (int tt = 0; tt < 16; ++tt) {
      int t = tgrp*16 + tt;
      float a = 0.f;
#pragma unroll
      for (int c = 0; c < 16; ++c)
        a = dot8v(wr[c], ((const uint4*)sEg)[SWU128(t, c)], a);
      ((ushort*)sP)[SB16(t, oq)] = f16u(K2E*(a + bo));
    }
  }
  __syncthreads();

  /* ---- stage4: pointer logits + log_softmax -> out ---- */
  {
    float A0[8], A1[8], acc0[8], acc1[8];
#pragma unroll
    for (int j = 0; j < 8; ++j) {
      float2 q = up16(sP[SWU32(w*8+j, lane)]);
      A0[j] = fexp2(q.x); A1[j] = fexp2(q.y);
      acc0[j] = 0.f; acc1[j] = 0.f;
    }
    attn_core(sEpx, lane, P2a, P2b, A0, A1, acc0, acc1);
#pragma unroll
    for (int j = 0; j < 8; ++j) {
      int t = w*8 + j;
      float u0 = Spv - acc0[j], u1 = Spv - acc1[j];
      /* logits = 10*tanh(u) = 10 - 20*rcp(1+exp2(K*u)) */
      float lg0 = fmaf(-20.f, frcp(1.f + fexp2(K2E*u0)), 10.f);
      float lg1 = fmaf(-20.f, frcp(1.f + fexp2(K2E*u1)), 10.f);
      if (rank0 < t) lg0 = NEG9;
      if (rank1 < t) lg1 = NEG9;
      float mx = fmaxf(lg0, lg1);
#pragma unroll
      for (int off = 32; off; off >>= 1) mx = fmaxf(mx, __shfl_xor(mx, off, 64));
      float ex0 = fexp2((lg0 - mx)*L2E), ex1 = fexp2((lg1 - mx)*L2E);
      float sm = ex0 + ex1;
#pragma unroll
      for (int off = 32; off; off >>= 1) sm += __shfl_xor(sm, off, 64);
      float lnS = flog2(sm) * LN2f;
      *(float2*)(out + (size_t)b*16384 + (size_t)t*128 + 2*lane) =
          make_float2(lg0 - mx - lnS, lg1 - mx - lnS);
    }
  }
}

extern "C" void kernel_launch(void* const* d_in, const int* in_sizes, int n_in,
                              void* d_out, int out_size, void* d_ws, size_t ws_size,
                              hipStream_t stream) {
  const float* dec   = (const float*)d_in[0];
  const float* emb   = (const float*)d_in[1];
  const float* h0    = (const float*)d_in[2];
  const float* c0    = (const float*)d_in[3];
  const float* ctx   = (const float*)d_in[4];
  const float* W_ih  = (const float*)d_in[5];
  const float* W_hh  = (const float*)d_in[6];
  const float* b_ih  = (const float*)d_in[7];
  const float* b_hh  = (const float*)d_in[8];
  const float* gWq   = (const float*)d_in[9];
  const float* gbq   = (const float*)d_in[10];
  const float* gWref = (const float*)d_in[11];
  const float* gbref = (const float*)d_in[12];
  const float* gv    = (const float*)d_in[13];
  const float* pWq   = (const float*)d_in[14];
  const float* pbq   = (const float*)d_in[15];
  const float* pWref = (const float*)d_in[16];
  const float* pbref = (const float*)d_in[17];
  const float* pv    = (const float*)d_in[18];
  const int*   eval  = (const int*)d_in[19];
  float* out = (float*)d_out;
  (void)in_sizes; (void)n_in; (void)out_size; (void)d_ws; (void)ws_size;

  hipLaunchKernelGGL(k_lstm, dim3(256), dim3(1024), 0, stream,
                     dec, emb, h0, c0, W_ih, W_hh, b_ih, b_hh, gWq, gbq, eval, out);
  hipLaunchKernelGGL(k_attn, dim3(1024), dim3(1024), 0, stream,
                     ctx, gWref, gbref, gv, pWq, pbq, pWref, pbref, pv, eval, out);
}

// Round 7
// 1647.225 us; speedup vs baseline: 1.5569x; 1.0014x over previous
//
#include <hip/hip_runtime.h>

#define NEG9 (-1e9f)
#define K2E  2.885390081777927f    /* 2*log2(e): tanh(z)=1-2/(1+exp2(K2E*z)) */
#define L2E  1.4426950408889634f
#define LN2f 0.6931471805599453f

#define OUT_SEL  16777216
#define OUT_HF   16908288
#define OUT_CF   17039360

typedef _Float16 half2_t __attribute__((ext_vector_type(2)));

static __device__ __forceinline__ float fexp2(float x){
#if __has_builtin(__builtin_amdgcn_exp2f)
  return __builtin_amdgcn_exp2f(x);
#else
  return exp2f(x);
#endif
}
static __device__ __forceinline__ float frcp(float x){
#if __has_builtin(__builtin_amdgcn_rcpf)
  return __builtin_amdgcn_rcpf(x);
#else
  return 1.0f / x;
#endif
}
static __device__ __forceinline__ float flog2(float x){
#if __has_builtin(__builtin_amdgcn_logf)
  return __builtin_amdgcn_logf(x);
#else
  return log2f(x);
#endif
}
static __device__ __forceinline__ uint pk16(float a, float b){
#if __has_builtin(__builtin_amdgcn_cvt_pkrtz)
  auto h = __builtin_amdgcn_cvt_pkrtz(a, b);           /* v_cvt_pkrtz_f16_f32 */
  union U { decltype(h) h2; uint u; } c; c.h2 = h; return c.u;
#else
  union { _Float16 h[2]; uint u; } c; c.h[0] = (_Float16)a; c.h[1] = (_Float16)b; return c.u;
#endif
}
static __device__ __forceinline__ ushort f16u(float a){
  return (ushort)(pk16(a, 0.f) & 0xffffu);
}
static __device__ __forceinline__ float2 up16(uint u){
  union { uint u; _Float16 h[2]; } c; c.u = u;
  return make_float2((float)c.h[0], (float)c.h[1]);
}
static __device__ __forceinline__ float fdot2(uint a, uint b, float acc){
#if __has_builtin(__builtin_amdgcn_fdot2)
  union { uint u; half2_t h; } ua, ub; ua.u = a; ub.u = b;
  return __builtin_amdgcn_fdot2(ua.h, ub.h, acc, false);
#else
  float2 fa = up16(a), fb = up16(b);
  return acc + fa.x * fb.x + fa.y * fb.y;
#endif
}
static __device__ __forceinline__ float dot8v(uint4 w, uint4 x, float acc){
  acc = fdot2(w.x, x.x, acc); acc = fdot2(w.y, x.y, acc);
  acc = fdot2(w.z, x.z, acc); acc = fdot2(w.w, x.w, acc);
  return acc;
}
static __device__ __forceinline__ float rdlane(float v, int i){
#if __has_builtin(__builtin_amdgcn_readlane)
  return __uint_as_float(__builtin_amdgcn_readlane(__float_as_uint(v), i));
#else
  return __shfl(v, i, 64);
#endif
}
static __device__ __forceinline__ float sigm(float x){
  return frcp(1.0f + fexp2(-L2E * x));
}
static __device__ __forceinline__ float tanh_(float x){
  return 1.0f - 2.0f * frcp(1.0f + fexp2(K2E * x));
}

/* swizzles for [128 rows][256B] f16 tiles.
   SWU*: standard (r&7) XOR (per-lane consecutive rows).
   SWT*: (r>>1)&7 XOR — for reads where lane L owns rows 2L,2L+1 (even rows
         would collapse to 4 slots under the standard pattern). */
#define SWU128(r,c) (((r)<<4)|((c)^((r)&7)))
#define SWT128(r,c) (((r)<<4)|((c)^(((r)>>1)&7)))
#define SWU32(r,d)  (((r)<<6)|((d)^(((r)&7)<<2)))
#define SB16(r,h)   (((r)<<7)|((((h)>>1)^(((r)&7)<<2))<<1)|((h)&1))
#define TB16(r,h)   (((r)<<7)|((((h)>>1)^((((r)>>1)&7)<<2))<<1)|((h)&1))

/* =====================================================================
 * K1: LSTM chain, 4 batch rows/block, 128 steps, 1024 threads.
 * Each thread holds ONE f16 weight row (W_ih or W_hh) in 16 uint4 regs.
 * __launch_bounds__(1024, 1): do NOT constrain VGPRs — wrow[16] is 64
 * VGPRs; the (1024,4) hint made the compiler allocate 64 total -> spill.
 * ===================================================================== */
__global__ __launch_bounds__(1024, 1) void k_lstm(
    const float* __restrict__ dec, const float* __restrict__ emb,
    const float* __restrict__ h0g, const float* __restrict__ c0g,
    const float* __restrict__ W_ih, const float* __restrict__ W_hh,
    const float* __restrict__ b_ih, const float* __restrict__ b_hh,
    const float* __restrict__ gWq, const float* __restrict__ gbq,
    const int* __restrict__ eval, float* __restrict__ out)
{
  __shared__ __align__(16) uint  sGwq[8192];       /* gWq f16 [128][128] swz: 32KB */
  __shared__ __align__(16) uint  sXbuf[4][64];     /* x f16 per row */
  __shared__ __align__(16) uint  sHbuf[4][64];     /* h f16 per row */
  __shared__ __align__(16) float sScr[2][4][512];  /* partial gates: 16KB */
  __shared__ float sC[4][128];
  __shared__ int   sEval[4][128];

  const int tid = threadIdx.x;
  const int b0  = blockIdx.x * 4;
  const int xh  = tid >> 9;        /* 0: x-side (W_ih), 1: h-side (W_hh) */
  const int o   = tid & 511;       /* gate-output row */

  /* ---- own weight row -> f16 regs (once) ---- */
  uint4 wrow[16];
  {
    const float4* src = (const float4*)((xh ? W_hh : W_ih) + (size_t)o * 128);
#pragma unroll
    for (int c = 0; c < 16; ++c) {
      float4 a = src[2*c], d = src[2*c+1];
      wrow[c] = make_uint4(pk16(a.x,a.y), pk16(a.z,a.w), pk16(d.x,d.y), pk16(d.z,d.w));
    }
  }
  /* ---- stage gWq f16 (swizzled) ---- */
  {
    int row = tid >> 3, hq = tid & 7;
    const float4* ws = (const float4*)(gWq + (size_t)row * 128 + hq * 16);
    float4 w0 = ws[0], w1 = ws[1], w2 = ws[2], w3 = ws[3];
    ((uint4*)sGwq)[SWU128(row, hq*2)] =
        make_uint4(pk16(w0.x,w0.y), pk16(w0.z,w0.w), pk16(w1.x,w1.y), pk16(w1.z,w1.w));
    ((uint4*)sGwq)[SWU128(row, hq*2+1)] =
        make_uint4(pk16(w2.x,w2.y), pk16(w2.z,w2.w), pk16(w3.x,w3.y), pk16(w3.z,w3.w));
  }
  /* ---- state init ---- */
  if (tid < 256) {
    int r = tid >> 6, d = tid & 63;
    float2 hv = *(const float2*)(h0g + (size_t)(b0+r)*128 + 2*d);
    sHbuf[r][d] = pk16(hv.x, hv.y);
    float2 xv = *(const float2*)(dec + (size_t)(b0+r)*128 + 2*d);
    sXbuf[r][d] = pk16(xv.x, xv.y);
  }
  if (tid >= 512) {
    int t2 = tid - 512, r = t2 >> 7, m = t2 & 127;
    sC[r][m] = c0g[(size_t)(b0+r)*128 + m];
    int ev = eval[(size_t)(b0+r)*128 + m];
    sEval[r][m] = ev;
    out[OUT_SEL + (size_t)(b0+r)*128 + m] = (float)ev;
  }
  const int rC = (tid >> 7) & 3, mC = tid & 127;
  float bi0=0,bi1=0,bi2=0,bi3=0, bh0=0,bh1=0,bh2=0,bh3=0, gbqv=0;
  if (tid < 512) {
    bi0 = b_ih[mC];     bh0 = b_hh[mC];
    bi1 = b_ih[128+mC]; bh1 = b_hh[128+mC];
    bi2 = b_ih[256+mC]; bh2 = b_hh[256+mC];
    bi3 = b_ih[384+mC]; bh3 = b_hh[384+mC];
    gbqv = gbq[mC];
  }
  __syncthreads();

  for (int t = 0; t < 128; ++t) {
    /* ---- phase1: gate dots (x-side from sXbuf, h-side from sHbuf) ---- */
    {
      const uint4* xb = (const uint4*)(xh ? &sHbuf[0][0] : &sXbuf[0][0]);
      float a0=0.f, a1=0.f, a2=0.f, a3=0.f;
#pragma unroll
      for (int c = 0; c < 16; ++c) {
        a0 = dot8v(wrow[c], xb[c],      a0);
        a1 = dot8v(wrow[c], xb[16+c],   a1);
        a2 = dot8v(wrow[c], xb[32+c],   a2);
        a3 = dot8v(wrow[c], xb[48+c],   a3);
      }
      sScr[xh][0][o] = a0; sScr[xh][1][o] = a1;
      sScr[xh][2][o] = a2; sScr[xh][3][o] = a3;
    }
    __syncthreads();

    /* ---- phase2: combine (tid<512) | x-prefetch (512..767) ---- */
    if (tid < 512) {
      float p0 = sScr[0][rC][mC]     + sScr[1][rC][mC]     + bi0 + bh0;
      float p1 = sScr[0][rC][128+mC] + sScr[1][rC][128+mC] + bi1 + bh1;
      float p2 = sScr[0][rC][256+mC] + sScr[1][rC][256+mC] + bi2 + bh2;
      float p3 = sScr[0][rC][384+mC] + sScr[1][rC][384+mC] + bi3 + bh3;
      float ii = sigm(p0), ff = sigm(p1), gg = tanh_(p2), oo = sigm(p3);
      float cc = ff * sC[rC][mC] + ii * gg;
      sC[rC][mC] = cc;
      float hh = oo * tanh_(cc);
      ((ushort*)sHbuf)[rC*128 + mC] = f16u(hh);
      if (t == 127) {
        out[OUT_HF + (size_t)(b0+rC)*128 + mC] = hh;
        out[OUT_CF + (size_t)(b0+rC)*128 + mC] = cc;
      }
    } else if (tid < 768) {
      int t2 = tid - 512, r = t2 >> 6, d = t2 & 63;
      int idx = sEval[r][t];       /* teacher forcing: x_{t+1} = emb[tour[t]] */
      float2 xv = *(const float2*)(emb + (size_t)idx*131072 + (size_t)(b0+r)*128 + 2*d);
      sXbuf[r][d] = pk16(xv.x, xv.y);
    }
    __syncthreads();

    /* ---- phase3: Kqq = K2E*(h2@gWq.T + gbq) -> out ---- */
    if (tid < 512) {
      const uint4* hb = (const uint4*)&sHbuf[rC][0];
      float qa = 0.f;
#pragma unroll
      for (int c = 0; c < 16; ++c)
        qa = dot8v(((const uint4*)sGwq)[SWU128(mC, c)], hb[c], qa);
      out[(size_t)(b0+rC)*16384 + (size_t)t*128 + mC] = K2E * (qa + gbqv);
    }
    __syncthreads();
  }
}

/* =====================================================================
 * K2: per-batch-row attention, 1024 threads, 16 waves (8 t per wave).
 * Buffers (32KB each):
 *  sEg : e_g f16 [o][l]      -> G_L f16 [t][h]
 *  sEx : E_g' f16 [l][h](T)  -> pWq f16 [o][h]
 *  sEpx: Wref f16 [o][h]     -> E_p' f16 [l][h](T)
 *  sP  : ctx f16 [l][h]      -> P f16 [t][l] -> qq_p f16 [t][o]
 * LDS = 128.5KB -> 1 block/CU regardless; launch_bounds(1024,1) frees
 * the register allocator (wr[16] = 64 VGPRs must be live in mat stages).
 * ===================================================================== */
static __device__ __forceinline__ void attn_core(
    const uint* __restrict__ Ebuf, int lane, float g0v, float g1v,
    const float* A0, const float* A1, float* acc0, float* acc1)
{
  for (int hq = 0; hq < 16; ++hq) {
    uint4 e0v = ((const uint4*)Ebuf)[SWT128(2*lane,   hq)];
    uint4 e1v = ((const uint4*)Ebuf)[SWT128(2*lane+1, hq)];
#define SUBSTEP(E0d, E1d, s) { \
    int hidx = hq*4 + (s); \
    float2 E0 = up16(E0d), E1 = up16(E1d); \
    float gh0 = rdlane(g0v, hidx), gh1 = rdlane(g1v, hidx); \
    _Pragma("unroll") \
    for (int j = 0; j < 8; ++j) { \
      float a0 = rdlane(A0[j], hidx), a1 = rdlane(A1[j], hidx); \
      acc0[j] += gh0*frcp(fmaf(a0, E0.x, 1.f)) + gh1*frcp(fmaf(a1, E0.y, 1.f)); \
      acc1[j] += gh0*frcp(fmaf(a0, E1.x, 1.f)) + gh1*frcp(fmaf(a1, E1.y, 1.f)); \
    } }
    SUBSTEP(e0v.x, e1v.x, 0)
    SUBSTEP(e0v.y, e1v.y, 1)
    SUBSTEP(e0v.z, e1v.z, 2)
    SUBSTEP(e0v.w, e1v.w, 3)
#undef SUBSTEP
  }
}

__global__ __launch_bounds__(1024, 1) void k_attn(
    const float* __restrict__ ctx,
    const float* __restrict__ gWref, const float* __restrict__ gbref,
    const float* __restrict__ gv,
    const float* __restrict__ pWq, const float* __restrict__ pbq,
    const float* __restrict__ pWref, const float* __restrict__ pbref,
    const float* __restrict__ pv,
    const int* __restrict__ eval,
    float* __restrict__ out)
{
  __shared__ __align__(16) uint sEg[8192];
  __shared__ __align__(16) uint sEx[8192];
  __shared__ __align__(16) uint sEpx[8192];
  __shared__ __align__(16) uint sP[8192];
  __shared__ int sRank[128];

  const int tid  = threadIdx.x;
  const int b    = blockIdx.x;
  const int lane = tid & 63, w = tid >> 6;

  if (tid < 128) sRank[eval[(size_t)b*128 + tid]] = tid;

  /* ---- stage ctx->sP f16 [l][h], gWref->sEpx f16 [o][h] ---- */
  {
    int row = tid >> 3, hq = tid & 7;
    const float4* cs = (const float4*)(ctx + (size_t)row*131072 + (size_t)b*128 + hq*16);
    float4 c0 = cs[0], c1 = cs[1], c2 = cs[2], c3 = cs[3];
    ((uint4*)sP)[SWU128(row, hq*2)] =
        make_uint4(pk16(c0.x,c0.y), pk16(c0.z,c0.w), pk16(c1.x,c1.y), pk16(c1.z,c1.w));
    ((uint4*)sP)[SWU128(row, hq*2+1)] =
        make_uint4(pk16(c2.x,c2.y), pk16(c2.z,c2.w), pk16(c3.x,c3.y), pk16(c3.z,c3.w));
    const float4* ws = (const float4*)(gWref + (size_t)row*128 + hq*16);
    float4 w0 = ws[0], w1 = ws[1], w2 = ws[2], w3 = ws[3];
    ((uint4*)sEpx)[SWU128(row, hq*2)] =
        make_uint4(pk16(w0.x,w0.y), pk16(w0.z,w0.w), pk16(w1.x,w1.y), pk16(w1.z,w1.w));
    ((uint4*)sEpx)[SWU128(row, hq*2+1)] =
        make_uint4(pk16(w2.x,w2.y), pk16(w2.z,w2.w), pk16(w3.x,w3.y), pk16(w3.z,w3.w));
  }
  float Sgv = 0.f, Spv = 0.f;
  for (int i = 0; i < 128; i += 4) {
    float4 g4 = *(const float4*)(gv + i); Sgv += g4.x + g4.y + g4.z + g4.w;
    float4 p4 = *(const float4*)(pv + i); Spv += p4.x + p4.y + p4.z + p4.w;
  }
  const float G2a = 2.f*gv[2*lane], G2b = 2.f*gv[2*lane+1];
  const float P2a = 2.f*pv[2*lane], P2b = 2.f*pv[2*lane+1];
  __syncthreads();
  const int rank0 = sRank[2*lane], rank1 = sRank[2*lane+1];

  /* 8 l-groups x 16 l's each = full 128 coverage */
  const int o_ = tid & 127, lgrp = tid >> 7, l0_ = lgrp * 16;

  /* ---- mat0: e_g [o][l] + E_g' [l][h] ---- */
  {
    uint4 wr[16];
#pragma unroll
    for (int c = 0; c < 16; ++c) wr[c] = ((const uint4*)sEpx)[SWU128(o_, c)];
    float bo = gbref[o_];
    float e[16];
#pragma unroll
    for (int j = 0; j < 16; ++j) {
      float a = 0.f;
#pragma unroll
      for (int c = 0; c < 16; ++c)
        a = dot8v(wr[c], ((const uint4*)sP)[SWU128(l0_+j, c)], a);
      e[j] = a + bo;
    }
    ((uint4*)sEg)[SWU128(o_, lgrp*2)] =
        make_uint4(pk16(e[0],e[1]), pk16(e[2],e[3]), pk16(e[4],e[5]), pk16(e[6],e[7]));
    ((uint4*)sEg)[SWU128(o_, lgrp*2+1)] =
        make_uint4(pk16(e[8],e[9]), pk16(e[10],e[11]), pk16(e[12],e[13]), pk16(e[14],e[15]));
#pragma unroll
    for (int j = 0; j < 16; ++j)
      ((ushort*)sEx)[TB16(l0_+j, o_)] = f16u(fexp2(K2E*e[j]));
  }
  __syncthreads();
  /* ---- restage pWref -> sEpx ---- */
  {
    int row = tid >> 3, hq = tid & 7;
    const float4* ws = (const float4*)(pWref + (size_t)row*128 + hq*16);
    float4 w0 = ws[0], w1 = ws[1], w2 = ws[2], w3 = ws[3];
    ((uint4*)sEpx)[SWU128(row, hq*2)] =
        make_uint4(pk16(w0.x,w0.y), pk16(w0.z,w0.w), pk16(w1.x,w1.y), pk16(w1.z,w1.w));
    ((uint4*)sEpx)[SWU128(row, hq*2+1)] =
        make_uint4(pk16(w2.x,w2.y), pk16(w2.z,w2.w), pk16(w3.x,w3.y), pk16(w3.z,w3.w));
  }
  __syncthreads();
  /* ---- mat1: e_p -> regs (full 16 l's per thread) ---- */
  float ep[16];
  {
    uint4 wr[16];
#pragma unroll
    for (int c = 0; c < 16; ++c) wr[c] = ((const uint4*)sEpx)[SWU128(o_, c)];
    float bo = pbref[o_];
#pragma unroll
    for (int j = 0; j < 16; ++j) {
      float a = 0.f;
#pragma unroll
      for (int c = 0; c < 16; ++c)
        a = dot8v(wr[c], ((const uint4*)sP)[SWU128(l0_+j, c)], a);
      ep[j] = a + bo;
    }
  }
  __syncthreads();
#pragma unroll
  for (int j = 0; j < 16; ++j)
    ((ushort*)sEpx)[TB16(l0_+j, o_)] = f16u(fexp2(K2E*ep[j]));   /* E_p' */

  /* ---- stage1: glimpse logits + softmax -> P [t][l] f16 ---- */
  {
    float A0[8], A1[8], acc0[8], acc1[8];
#pragma unroll
    for (int j = 0; j < 8; ++j) {
      float2 qq = *(const float2*)(out + (size_t)b*16384 + (size_t)(w*8+j)*128 + 2*lane);
      A0[j] = fexp2(qq.x); A1[j] = fexp2(qq.y);
      acc0[j] = 0.f; acc1[j] = 0.f;
    }
    attn_core(sEx, lane, G2a, G2b, A0, A1, acc0, acc1);
#pragma unroll
    for (int j = 0; j < 8; ++j) {
      int t = w*8 + j;
      float u0 = Sgv - acc0[j], u1 = Sgv - acc1[j];
      if (rank0 < t) u0 = NEG9;
      if (rank1 < t) u1 = NEG9;
      float mx = fmaxf(u0, u1);
#pragma unroll
      for (int off = 32; off; off >>= 1) mx = fmaxf(mx, __shfl_xor(mx, off, 64));
      float ex0 = fexp2((u0 - mx)*L2E), ex1 = fexp2((u1 - mx)*L2E);
      float sm = ex0 + ex1;
#pragma unroll
      for (int off = 32; off; off >>= 1) sm += __shfl_xor(sm, off, 64);
      float rs = frcp(sm);
      sP[SWU32(t, lane)] = pk16(ex0*rs, ex1*rs);
    }
  }
  __syncthreads();

  /* ---- stage2: G_L[t][h] = sum_l e_g[h][l]*P[t][l]; stage pWq->sEx ---- */
  {
    const int h = tid & 127, tgrp = tid >> 7;
    uint4 wr[16];
#pragma unroll
    for (int c = 0; c < 16; ++c) wr[c] = ((const uint4*)sEg)[SWU128(h, c)];
    {
      int row = tid >> 3, hq = tid & 7;
      const float4* ws = (const float4*)(pWq + (size_t)row*128 + hq*16);
      float4 w0 = ws[0], w1 = ws[1], w2 = ws[2], w3 = ws[3];
      ((uint4*)sEx)[SWU128(row, hq*2)] =
          make_uint4(pk16(w0.x,w0.y), pk16(w0.z,w0.w), pk16(w1.x,w1.y), pk16(w1.z,w1.w));
      ((uint4*)sEx)[SWU128(row, hq*2+1)] =
          make_uint4(pk16(w2.x,w2.y), pk16(w2.z,w2.w), pk16(w3.x,w3.y), pk16(w3.z,w3.w));
    }
    __syncthreads();          /* all e_g reads staged to regs; sEg now writable */
    for (int tt = 0; tt < 16; ++tt) {
      int t = tgrp*16 + tt;
      float a = 0.f;
#pragma unroll
      for (int c = 0; c < 16; ++c)
        a = dot8v(wr[c], ((const uint4*)sP)[SWU128(t, c)], a);
      ((ushort*)sEg)[SB16(t, h)] = f16u(a);
    }
  }
  __syncthreads();

  /* ---- stage3: qq_p[t][o] = K2E*(G_L[t]@pWq[o] + pbq[o]) -> sP [t][o] f16 ---- */
  {
    const int oq = tid & 127, tgrp = tid >> 7;
    uint4 wr[16];
#pragma unroll
    for (int c = 0; c < 16; ++c) wr[c] = ((const uint4*)sEx)[SWU128(oq, c)];
    float bo = pbq[oq];
    for (int tt = 0; tt < 16; ++tt) {
      int t = tgrp*16 + tt;
      float a = 0.f;
#pragma unroll
      for (int c = 0; c < 16; ++c)
        a = dot8v(wr[c], ((const uint4*)sEg)[SWU128(t, c)], a);
      ((ushort*)sP)[SB16(t, oq)] = f16u(K2E*(a + bo));
    }
  }
  __syncthreads();

  /* ---- stage4: pointer logits + log_softmax -> out ---- */
  {
    float A0[8], A1[8], acc0[8], acc1[8];
#pragma unroll
    for (int j = 0; j < 8; ++j) {
      float2 q = up16(sP[SWU32(w*8+j, lane)]);
      A0[j] = fexp2(q.x); A1[j] = fexp2(q.y);
      acc0[j] = 0.f; acc1[j] = 0.f;
    }
    attn_core(sEpx, lane, P2a, P2b, A0, A1, acc0, acc1);
#pragma unroll
    for (int j = 0; j < 8; ++j) {
      int t = w*8 + j;
      float u0 = Spv - acc0[j], u1 = Spv - acc1[j];
      /* logits = 10*tanh(u) = 10 - 20*rcp(1+exp2(K*u)) */
      float lg0 = fmaf(-20.f, frcp(1.f + fexp2(K2E*u0)), 10.f);
      float lg1 = fmaf(-20.f, frcp(1.f + fexp2(K2E*u1)), 10.f);
      if (rank0 < t) lg0 = NEG9;
      if (rank1 < t) lg1 = NEG9;
      float mx = fmaxf(lg0, lg1);
#pragma unroll
      for (int off = 32; off; off >>= 1) mx = fmaxf(mx, __shfl_xor(mx, off, 64));
      float ex0 = fexp2((lg0 - mx)*L2E), ex1 = fexp2((lg1 - mx)*L2E);
      float sm = ex0 + ex1;
#pragma unroll
      for (int off = 32; off; off >>= 1) sm += __shfl_xor(sm, off, 64);
      float lnS = flog2(sm) * LN2f;
      *(float2*)(out + (size_t)b*16384 + (size_t)t*128 + 2*lane) =
          make_float2(lg0 - mx - lnS, lg1 - mx - lnS);
    }
  }
}

extern "C" void kernel_launch(void* const* d_in, const int* in_sizes, int n_in,
                              void* d_out, int out_size, void* d_ws, size_t ws_size,
                              hipStream_t stream) {
  const float* dec   = (const float*)d_in[0];
  const float* emb   = (const float*)d_in[1];
  const float* h0    = (const float*)d_in[2];
  const float* c0    = (const float*)d_in[3];
  const float* ctx   = (const float*)d_in[4];
  const float* W_ih  = (const float*)d_in[5];
  const float* W_hh  = (const float*)d_in[6];
  const float* b_ih  = (const float*)d_in[7];
  const float* b_hh  = (const float*)d_in[8];
  const float* gWq   = (const float*)d_in[9];
  const float* gbq   = (const float*)d_in[10];
  const float* gWref = (const float*)d_in[11];
  const float* gbref = (const float*)d_in[12];
  const float* gv    = (const float*)d_in[13];
  const float* pWq   = (const float*)d_in[14];
  const float* pbq   = (const float*)d_in[15];
  const float* pWref = (const float*)d_in[16];
  const float* pbref = (const float*)d_in[17];
  const float* pv    = (const float*)d_in[18];
  const int*   eval  = (const int*)d_in[19];
  float* out = (float*)d_out;
  (void)in_sizes; (void)n_in; (void)out_size; (void)d_ws; (void)ws_size;

  hipLaunchKernelGGL(k_lstm, dim3(256), dim3(1024), 0, stream,
                     dec, emb, h0, c0, W_ih, W_hh, b_ih, b_hh, gWq, gbq, eval, out);
  hipLaunchKernelGGL(k_attn, dim3(1024), dim3(1024), 0, stream,
                     ctx, gWref, gbref, gv, pWq, pbq, pWref, pbref, pv, eval, out);
}